// Round 2
// baseline (2998.461 us; speedup 1.0000x reference)
//
#include <hip/hip_runtime.h>
#include <math.h>

#define B_ 8
#define S_ 1024
#define D_ 1024
#define H_ 16
#define DH_ 64
#define FFN_ 4096
#define NEG_ (-1e9f)
#define EPS_ 1e-5f

// ---------------------------------------------------------------------------
// Weight packing
// ---------------------------------------------------------------------------

// out[k][qkv*1024 + h*64 + e] = W{q,k,v}[h][k][e]
__global__ __launch_bounds__(256) void pack_qkv_k(
    const float* __restrict__ Wq, const float* __restrict__ Wk,
    const float* __restrict__ Wv, float* __restrict__ out) {
  int idx = blockIdx.x * 256 + threadIdx.x;        // 1024*3072 total
  int n = idx % 3072;
  int k = idx / 3072;
  int which = n >> 10, hn = n & 1023;
  int h = hn >> 6, e = hn & 63;
  const float* W = (which == 0) ? Wq : (which == 1 ? Wk : Wv);
  out[idx] = W[((size_t)h * D_ + k) * DH_ + e];
}

// in[R][C] -> out[C][R]
template <int R, int C>
__global__ __launch_bounds__(256) void transpose_k(const float* __restrict__ in,
                                                   float* __restrict__ out) {
  __shared__ float tile[32][33];
  int bx = blockIdx.x % (C / 32);
  int by = blockIdx.x / (C / 32);
  int tx = threadIdx.x % 32, ty = threadIdx.x / 32;  // 32x8
#pragma unroll
  for (int i = 0; i < 32; i += 8)
    tile[ty + i][tx] = in[(size_t)(by * 32 + ty + i) * C + bx * 32 + tx];
  __syncthreads();
#pragma unroll
  for (int i = 0; i < 32; i += 8)
    out[(size_t)(bx * 32 + ty + i) * R + by * 32 + tx] = tile[tx][ty + i];
}

// ---------------------------------------------------------------------------
// fp32 GEMM: C[M][N] = act(A[M][K] @ Bp[K][N] + bias)
// 128x128 tile, K-step 16, 256 threads, 8x8 microtile/thread
// ---------------------------------------------------------------------------
template <int BIAS, int RELU>
__global__ __launch_bounds__(256) void gemm_f32(
    const float* __restrict__ A, const float* __restrict__ Bp,
    const float* __restrict__ bias, float* __restrict__ C,
    int M, int N, int K) {
  __shared__ float As[16][128];  // [k][row]  (A stored transposed)
  __shared__ float Bs[16][128];  // [k][col]
  const int nb = N >> 7;
  const int bm = blockIdx.x / nb, bn = blockIdx.x % nb;
  const int t = threadIdx.x;
  const int tx = t & 15, ty = t >> 4;
  const int row0 = bm << 7, col0 = bn << 7;

  float acc[8][8] = {};
  const float* Aptr = A + (size_t)row0 * K;
  const float* Bptr = Bp + col0;

  for (int k0 = 0; k0 < K; k0 += 16) {
    float4 av[2], bv[2];
#pragma unroll
    for (int i = 0; i < 2; i++) {
      int j = t + i * 256;
      int ar = j >> 2, akq = j & 3;                 // A: row, k-quarter
      av[i] = *(const float4*)(Aptr + (size_t)ar * K + k0 + akq * 4);
      int bk = j >> 5, bn4 = j & 31;                // B: k, n-quarter
      bv[i] = *(const float4*)(Bptr + (size_t)(k0 + bk) * N + bn4 * 4);
    }
    __syncthreads();
#pragma unroll
    for (int i = 0; i < 2; i++) {
      int j = t + i * 256;
      int ar = j >> 2, akq = j & 3;
      As[akq * 4 + 0][ar] = av[i].x;
      As[akq * 4 + 1][ar] = av[i].y;
      As[akq * 4 + 2][ar] = av[i].z;
      As[akq * 4 + 3][ar] = av[i].w;
      int bk = j >> 5, bn4 = j & 31;
      *(float4*)&Bs[bk][bn4 * 4] = bv[i];
    }
    __syncthreads();
#pragma unroll
    for (int kk = 0; kk < 16; kk++) {
      float a[8], b[8];
      *(float4*)&a[0] = *(const float4*)&As[kk][ty * 8];
      *(float4*)&a[4] = *(const float4*)&As[kk][ty * 8 + 4];
      *(float4*)&b[0] = *(const float4*)&Bs[kk][tx * 8];
      *(float4*)&b[4] = *(const float4*)&Bs[kk][tx * 8 + 4];
#pragma unroll
      for (int i = 0; i < 8; i++)
#pragma unroll
        for (int j = 0; j < 8; j++)
          acc[i][j] = fmaf(a[i], b[j], acc[i][j]);
    }
  }

#pragma unroll
  for (int i = 0; i < 8; i++) {
    int r = row0 + ty * 8 + i;
#pragma unroll
    for (int j = 0; j < 8; j += 4) {
      int c = col0 + tx * 8 + j;
      float4 v = *(float4*)&acc[i][j];
      if (BIAS) {
        v.x += bias[c]; v.y += bias[c + 1]; v.z += bias[c + 2]; v.w += bias[c + 3];
      }
      if (RELU) {
        v.x = fmaxf(v.x, 0.f); v.y = fmaxf(v.y, 0.f);
        v.z = fmaxf(v.z, 0.f); v.w = fmaxf(v.w, 0.f);
      }
      *(float4*)(C + (size_t)r * N + c) = v;
    }
  }
}

// ---------------------------------------------------------------------------
// Flash-style fp32 attention. qkv layout: [B*S][3072] (q|k|v, each h*64+e).
// One block per (b, h, 64-row q-tile). 256 thr: ti=t/16 (4 rows), tj=t%16
// (4 keys / 4 out-dims). Fully-masked key tiles skipped (exact: exp->0).
// ---------------------------------------------------------------------------
__global__ __launch_bounds__(256) void attention_k(
    const float* __restrict__ qkv, const int* __restrict__ lens,
    float* __restrict__ concat) {
  __shared__ float Qt[64][64];  // [d][row]
  __shared__ float Kt[64][64];  // [d][key]
  __shared__ float Vs[64][64];  // [key][d]
  __shared__ float Pt[64][64];  // [key][row]
  const int blk = blockIdx.x;
  const int b = blk >> 8, rem = blk & 255;
  const int h = rem >> 4, q0 = (rem & 15) << 6;
  const int t = threadIdx.x;
  const int ti = t >> 4, tj = t & 15;
  const int len_b = lens[b];

  // load Q tile (transposed): 64 rows x 64 dims = 1024 float4, 4 per thread
#pragma unroll
  for (int i = 0; i < 4; i++) {
    int idx = t + i * 256;
    int r = idx >> 4, eq = idx & 15;
    const float* src =
        qkv + ((size_t)(b * S_ + q0 + r)) * 3072 + h * 64 + eq * 4;
    float4 v = *(const float4*)src;
    Qt[eq * 4 + 0][r] = v.x; Qt[eq * 4 + 1][r] = v.y;
    Qt[eq * 4 + 2][r] = v.z; Qt[eq * 4 + 3][r] = v.w;
  }

  float m[4], l[4], o[4][4];
#pragma unroll
  for (int i = 0; i < 4; i++) {
    m[i] = -INFINITY; l[i] = 0.f;
#pragma unroll
    for (int j = 0; j < 4; j++) o[i][j] = 0.f;
  }

  for (int j0 = 0; j0 < len_b; j0 += 64) {
    __syncthreads();  // previous tile's Kt/Vs/Pt reads done
    // load K (transposed) and V tiles: 4 float4 each per thread
#pragma unroll
    for (int i = 0; i < 4; i++) {
      int idx = t + i * 256;
      int r = idx >> 4, eq = idx & 15;
      const float* base =
          qkv + ((size_t)(b * S_ + j0 + r)) * 3072 + h * 64 + eq * 4;
      float4 kv = *(const float4*)(base + 1024);
      Kt[eq * 4 + 0][r] = kv.x; Kt[eq * 4 + 1][r] = kv.y;
      Kt[eq * 4 + 2][r] = kv.z; Kt[eq * 4 + 3][r] = kv.w;
      *(float4*)&Vs[r][eq * 4] = *(const float4*)(base + 2048);
    }
    __syncthreads();

    // QK^T
    float s[4][4] = {};
#pragma unroll 4
    for (int d = 0; d < 64; d++) {
      float qa[4], kb[4];
      *(float4*)qa = *(const float4*)&Qt[d][ti * 4];
      *(float4*)kb = *(const float4*)&Kt[d][tj * 4];
#pragma unroll
      for (int i = 0; i < 4; i++)
#pragma unroll
        for (int j = 0; j < 4; j++)
          s[i][j] = fmaf(qa[i], kb[j], s[i][j]);
    }

    // scale + mask + online softmax
#pragma unroll
    for (int i = 0; i < 4; i++) {
#pragma unroll
      for (int j = 0; j < 4; j++) {
        float v = s[i][j] * 0.125f;
        if (j0 + tj * 4 + j >= len_b) v = NEG_;
        s[i][j] = v;
      }
      float a = fmaxf(fmaxf(s[i][0], s[i][1]), fmaxf(s[i][2], s[i][3]));
#pragma unroll
      for (int off = 1; off < 16; off <<= 1) a = fmaxf(a, __shfl_xor(a, off));
      float mn = fmaxf(m[i], a);
      float sc = __expf(m[i] - mn);
      float p0 = __expf(s[i][0] - mn), p1 = __expf(s[i][1] - mn);
      float p2 = __expf(s[i][2] - mn), p3 = __expf(s[i][3] - mn);
      float rs = p0 + p1 + p2 + p3;
#pragma unroll
      for (int off = 1; off < 16; off <<= 1) rs += __shfl_xor(rs, off);
      l[i] = l[i] * sc + rs;
      m[i] = mn;
      o[i][0] *= sc; o[i][1] *= sc; o[i][2] *= sc; o[i][3] *= sc;
      s[i][0] = p0; s[i][1] = p1; s[i][2] = p2; s[i][3] = p3;
    }

    // write P transposed: Pt[key][row]
#pragma unroll
    for (int jj = 0; jj < 4; jj++) {
      float4 pv = make_float4(s[0][jj], s[1][jj], s[2][jj], s[3][jj]);
      *(float4*)&Pt[tj * 4 + jj][ti * 4] = pv;
    }
    __syncthreads();

    // PV
#pragma unroll 4
    for (int j = 0; j < 64; j++) {
      float pa[4], vb[4];
      *(float4*)pa = *(const float4*)&Pt[j][ti * 4];
      *(float4*)vb = *(const float4*)&Vs[j][tj * 4];
#pragma unroll
      for (int i = 0; i < 4; i++)
#pragma unroll
        for (int jc = 0; jc < 4; jc++)
          o[i][jc] = fmaf(pa[i], vb[jc], o[i][jc]);
    }
  }

#pragma unroll
  for (int i = 0; i < 4; i++) {
    float inv = 1.0f / l[i];
    float4 v = make_float4(o[i][0] * inv, o[i][1] * inv, o[i][2] * inv, o[i][3] * inv);
    size_t row = (size_t)(b * S_ + q0 + ti * 4 + i);
    *(float4*)(concat + row * 1024 + h * 64 + tj * 4) = v;
  }
}

// ---------------------------------------------------------------------------
// y[row] = LayerNorm(a[row] + r[row]), rows of 1024
// ---------------------------------------------------------------------------
__global__ __launch_bounds__(256) void add_ln_k(const float* __restrict__ a,
                                                const float* __restrict__ r,
                                                float* __restrict__ y) {
  const int row = blockIdx.x, t = threadIdx.x;
  const float4 av = ((const float4*)(a + (size_t)row * 1024))[t];
  const float4 rv = ((const float4*)(r + (size_t)row * 1024))[t];
  float v[4] = {av.x + rv.x, av.y + rv.y, av.z + rv.z, av.w + rv.w};
  float s = v[0] + v[1] + v[2] + v[3];
  float q = v[0] * v[0] + v[1] * v[1] + v[2] * v[2] + v[3] * v[3];
#pragma unroll
  for (int off = 1; off < 64; off <<= 1) {
    s += __shfl_xor(s, off);
    q += __shfl_xor(q, off);
  }
  __shared__ float ss[4], sq[4];
  int wave = t >> 6, lane = t & 63;
  if (lane == 0) { ss[wave] = s; sq[wave] = q; }
  __syncthreads();
  s = ss[0] + ss[1] + ss[2] + ss[3];
  q = sq[0] + sq[1] + sq[2] + sq[3];
  float mean = s * (1.f / 1024.f);
  float var = q * (1.f / 1024.f) - mean * mean;
  float inv = 1.0f / sqrtf(var + EPS_);
  float4 yo;
  yo.x = (v[0] - mean) * inv; yo.y = (v[1] - mean) * inv;
  yo.z = (v[2] - mean) * inv; yo.w = (v[3] - mean) * inv;
  ((float4*)(y + (size_t)row * 1024))[t] = yo;
}

// ---------------------------------------------------------------------------
extern "C" void kernel_launch(void* const* d_in, const int* in_sizes, int n_in,
                              void* d_out, int out_size, void* d_ws, size_t ws_size,
                              hipStream_t stream) {
  const float* x  = (const float*)d_in[0];
  const int* len  = (const int*)d_in[1];
  const float* Wq = (const float*)d_in[2];
  const float* Wk = (const float*)d_in[3];
  const float* Wv = (const float*)d_in[4];
  const float* Wo = (const float*)d_in[5];
  const float* W1 = (const float*)d_in[6];
  const float* b1 = (const float*)d_in[7];
  const float* W2 = (const float*)d_in[8];
  const float* b2 = (const float*)d_in[9];
  float* out = (float*)d_out;

  // workspace layout (floats); total 54,525,952 floats = ~208 MB
  if (ws_size < (size_t)54525952 * 4) return;  // insufficient ws -> fail loud
  float* ws       = (float*)d_ws;
  float* packqkv  = ws;                 // [1024][3072]  12 MB
  float* packwo   = ws + 3145728;       // [1024][1024]   4 MB
  float* packw1   = ws + 4194304;       // [1024][4096]  16 MB
  float* packw2   = ws + 8388608;       // [4096][1024]  16 MB
  float* qkv      = ws + 12582912;      // [8192][3072]  96 MB
  float* concat   = ws + 37748736;      // [8192][1024]  32 MB
  float* x1       = ws + 46137344;      // [8192][1024]  32 MB
  float* attnout  = qkv;                // reuse (qkv dead after attention)
  float* hidden   = qkv;                // reuse qkv+concat (128 MB)
  float* ffn2out  = ws;                 // reuse pack_qkv+pack_wo+pack_w1 (32 MB)

  pack_qkv_k<<<12288, 256, 0, stream>>>(Wq, Wk, Wv, packqkv);
  transpose_k<1024, 1024><<<1024, 256, 0, stream>>>(Wo, packwo);
  transpose_k<4096, 1024><<<4096, 256, 0, stream>>>(W1, packw1);
  transpose_k<1024, 4096><<<4096, 256, 0, stream>>>(W2, packw2);

  // QKV projection: [8192,1024] x [1024,3072]
  gemm_f32<0, 0><<<64 * 24, 256, 0, stream>>>(x, packqkv, nullptr, qkv,
                                              8192, 3072, 1024);
  attention_k<<<2048, 256, 0, stream>>>(qkv, len, concat);
  // output projection: [8192,1024] x [1024,1024]
  gemm_f32<0, 0><<<64 * 8, 256, 0, stream>>>(concat, packwo, nullptr, attnout,
                                             8192, 1024, 1024);
  add_ln_k<<<8192, 256, 0, stream>>>(x, attnout, x1);
  // FFN1: [8192,1024] x [1024,4096] + bias, relu
  gemm_f32<1, 1><<<64 * 32, 256, 0, stream>>>(x1, packw1, b1, hidden,
                                              8192, 4096, 1024);
  // FFN2: [8192,4096] x [4096,1024] + bias
  gemm_f32<1, 0><<<64 * 8, 256, 0, stream>>>(hidden, packw2, b2, ffn2out,
                                             8192, 1024, 4096);
  add_ln_k<<<8192, 256, 0, stream>>>(x1, ffn2out, out);
}

// Round 3
// 803.768 us; speedup vs baseline: 3.7305x; 3.7305x over previous
//
#include <hip/hip_runtime.h>
#include <hip/hip_bf16.h>
#include <math.h>

#define B_ 8
#define S_ 1024
#define D_ 1024
#define H_ 16
#define DH_ 64
#define FFN_ 4096
#define NEG_ (-1e9f)
#define EPS_ 1e-5f

typedef float f32x4 __attribute__((ext_vector_type(4)));
typedef short bf16x8 __attribute__((ext_vector_type(8)));

__device__ __forceinline__ ushort f2b(float f) {
  __hip_bfloat16 h = __float2bfloat16(f);  // RNE
  return *reinterpret_cast<ushort*>(&h);
}
__device__ __forceinline__ float b2f(ushort u) {
  return __uint_as_float((unsigned)u << 16);
}

__device__ __forceinline__ void gload16(const void* g, void* l) {
  auto* lp = (__attribute__((address_space(3))) unsigned*)(uintptr_t)(l);
  __builtin_amdgcn_global_load_lds(
      (const __attribute__((address_space(1))) unsigned*)g, lp, 16, 0, 0);
}

// ---------------------------------------------------------------------------
// casts / packing
// ---------------------------------------------------------------------------
__global__ __launch_bounds__(256) void cast_bf16_k(const float* __restrict__ in,
                                                   ushort* __restrict__ out,
                                                   int n4) {
  int i = blockIdx.x * 256 + threadIdx.x;
  if (i >= n4) return;
  float4 v = ((const float4*)in)[i];
  ushort4 o;
  o.x = f2b(v.x); o.y = f2b(v.y); o.z = f2b(v.z); o.w = f2b(v.w);
  ((ushort4*)out)[i] = o;
}

// qkvT[(which*1024 + h*64 + e)][k] = W{q,k,v}[h][k][e]   (bf16 out)
__global__ __launch_bounds__(256) void pack_qkvT_k(
    const float* __restrict__ Wq, const float* __restrict__ Wk,
    const float* __restrict__ Wv, ushort* __restrict__ out) {
  int idx = blockIdx.x * 256 + threadIdx.x;  // 3*16*1024*64
  int e = idx & 63, k = (idx >> 6) & 1023;
  int h = (idx >> 16) & 15, which = idx >> 20;
  const float* W = (which == 0) ? Wq : (which == 1 ? Wk : Wv);
  float v = W[((size_t)h * D_ + k) * DH_ + e];
  out[((size_t)which * 1024 + h * 64 + e) * 1024 + k] = f2b(v);
}

// ---------------------------------------------------------------------------
// bf16 MFMA GEMM (m97 structure): C[M][N] = act(A[M][K] @ Bt[N][K]^T + bias)
// 128x128 tile, BK=64, 256 thr = 4 waves (2x2), 64x64 per wave, 16x16x32 MFMA
// ---------------------------------------------------------------------------
template <int BIAS, int RELU, int OUT_BF16>
__global__ __launch_bounds__(256) void gemm_bf16(
    const ushort* __restrict__ A, const ushort* __restrict__ Bt,
    const float* __restrict__ bias, void* __restrict__ C,
    int M, int N, int K) {
  __shared__ ushort Al[128 * 64];
  __shared__ ushort Bl[128 * 64];
  const int nb = N >> 7;
  const int bm = blockIdx.x / nb, bn = blockIdx.x % nb;
  const int t = threadIdx.x;
  const int lane = t & 63;
  const int wid = t >> 6, wr = wid >> 1, wc = wid & 1;
  const int row0 = bm << 7, col0 = bn << 7;
  const size_t Kb = (size_t)K * 2;  // row stride bytes

  const char* Abase = (const char*)A + (size_t)row0 * Kb;
  const char* Bbase = (const char*)Bt + (size_t)col0 * Kb;

  f32x4 acc[4][4] = {};

  const int o0 = t * 16;  // linear byte offset this thread stages
  for (int k0 = 0; k0 < K; k0 += 64) {
#pragma unroll
    for (int i = 0; i < 4; i++) {
      int ob = o0 + i * 4096;
      int row = ob >> 7, inrow = ob & 127;
      const char* ga = Abase + (size_t)row * Kb + k0 * 2 + inrow;
      const char* gb = Bbase + (size_t)row * Kb + k0 * 2 + inrow;
      gload16(ga, (char*)Al + ob);
      gload16(gb, (char*)Bl + ob);
    }
    __syncthreads();
#pragma unroll
    for (int kk = 0; kk < 64; kk += 32) {
      bf16x8 af[4], bfr[4];
      const int lrow = lane & 15, lk = (lane >> 4) * 8 + kk;
#pragma unroll
      for (int m = 0; m < 4; m++)
        af[m] = *(const bf16x8*)&Al[(wr * 64 + m * 16 + lrow) * 64 + lk];
#pragma unroll
      for (int n = 0; n < 4; n++)
        bfr[n] = *(const bf16x8*)&Bl[(wc * 64 + n * 16 + lrow) * 64 + lk];
#pragma unroll
      for (int m = 0; m < 4; m++)
#pragma unroll
        for (int n = 0; n < 4; n++)
          acc[m][n] = __builtin_amdgcn_mfma_f32_16x16x32_bf16(
              af[m], bfr[n], acc[m][n], 0, 0, 0);
    }
    __syncthreads();
  }

  // epilogue: C/D layout col=lane&15, row=(lane>>4)*4+q
  const int rbase = row0 + wr * 64 + (lane >> 4) * 4;
  const int cbase = col0 + wc * 64 + (lane & 15);
#pragma unroll
  for (int m = 0; m < 4; m++) {
#pragma unroll
    for (int n = 0; n < 4; n++) {
      int col = cbase + n * 16;
      float bv = BIAS ? bias[col] : 0.0f;
#pragma unroll
      for (int q = 0; q < 4; q++) {
        int row = rbase + m * 16 + q;
        float v = acc[m][n][q] + bv;
        if (RELU) v = fmaxf(v, 0.0f);
        if (OUT_BF16)
          ((ushort*)C)[(size_t)row * N + col] = f2b(v);
        else
          ((float*)C)[(size_t)row * N + col] = v;
      }
    }
  }
}

// ---------------------------------------------------------------------------
// Flash-style fp32 attention over bf16 qkv [B*S][3072] (q|k|v, each h*64+e).
// One block per (b, h, 64-row q-tile). Writes concat bf16 [B*S][1024].
// ---------------------------------------------------------------------------
__global__ __launch_bounds__(256) void attention_k(
    const ushort* __restrict__ qkv, const int* __restrict__ lens,
    ushort* __restrict__ concat) {
  __shared__ float Qt[64][64];  // [d][row]
  __shared__ float Kt[64][64];  // [d][key]
  __shared__ float Vs[64][64];  // [key][d]
  __shared__ float Pt[64][64];  // [key][row]
  const int blk = blockIdx.x;
  const int b = blk >> 8, rem = blk & 255;
  const int h = rem >> 4, q0 = (rem & 15) << 6;
  const int t = threadIdx.x;
  const int ti = t >> 4, tj = t & 15;
  const int len_b = lens[b];

#pragma unroll
  for (int i = 0; i < 4; i++) {
    int idx = t + i * 256;
    int r = idx >> 4, eq = idx & 15;
    const ushort* src =
        qkv + ((size_t)(b * S_ + q0 + r)) * 3072 + h * 64 + eq * 4;
    ushort4 v = *(const ushort4*)src;
    Qt[eq * 4 + 0][r] = b2f(v.x); Qt[eq * 4 + 1][r] = b2f(v.y);
    Qt[eq * 4 + 2][r] = b2f(v.z); Qt[eq * 4 + 3][r] = b2f(v.w);
  }

  float m[4], l[4], o[4][4];
#pragma unroll
  for (int i = 0; i < 4; i++) {
    m[i] = -INFINITY; l[i] = 0.f;
#pragma unroll
    for (int j = 0; j < 4; j++) o[i][j] = 0.f;
  }

  for (int j0 = 0; j0 < len_b; j0 += 64) {
    __syncthreads();
#pragma unroll
    for (int i = 0; i < 4; i++) {
      int idx = t + i * 256;
      int r = idx >> 4, eq = idx & 15;
      const ushort* base =
          qkv + ((size_t)(b * S_ + j0 + r)) * 3072 + h * 64 + eq * 4;
      ushort4 kv = *(const ushort4*)(base + 1024);
      Kt[eq * 4 + 0][r] = b2f(kv.x); Kt[eq * 4 + 1][r] = b2f(kv.y);
      Kt[eq * 4 + 2][r] = b2f(kv.z); Kt[eq * 4 + 3][r] = b2f(kv.w);
      ushort4 vv = *(const ushort4*)(base + 2048);
      Vs[r][eq * 4 + 0] = b2f(vv.x); Vs[r][eq * 4 + 1] = b2f(vv.y);
      Vs[r][eq * 4 + 2] = b2f(vv.z); Vs[r][eq * 4 + 3] = b2f(vv.w);
    }
    __syncthreads();

    float s[4][4] = {};
#pragma unroll 4
    for (int d = 0; d < 64; d++) {
      float qa[4], kb[4];
      *(float4*)qa = *(const float4*)&Qt[d][ti * 4];
      *(float4*)kb = *(const float4*)&Kt[d][tj * 4];
#pragma unroll
      for (int i = 0; i < 4; i++)
#pragma unroll
        for (int j = 0; j < 4; j++)
          s[i][j] = fmaf(qa[i], kb[j], s[i][j]);
    }

#pragma unroll
    for (int i = 0; i < 4; i++) {
#pragma unroll
      for (int j = 0; j < 4; j++) {
        float v = s[i][j] * 0.125f;
        if (j0 + tj * 4 + j >= len_b) v = NEG_;
        s[i][j] = v;
      }
      float a = fmaxf(fmaxf(s[i][0], s[i][1]), fmaxf(s[i][2], s[i][3]));
#pragma unroll
      for (int off = 1; off < 16; off <<= 1) a = fmaxf(a, __shfl_xor(a, off));
      float mn = fmaxf(m[i], a);
      float sc = __expf(m[i] - mn);
      float p0 = __expf(s[i][0] - mn), p1 = __expf(s[i][1] - mn);
      float p2 = __expf(s[i][2] - mn), p3 = __expf(s[i][3] - mn);
      float rs = p0 + p1 + p2 + p3;
#pragma unroll
      for (int off = 1; off < 16; off <<= 1) rs += __shfl_xor(rs, off);
      l[i] = l[i] * sc + rs;
      m[i] = mn;
      o[i][0] *= sc; o[i][1] *= sc; o[i][2] *= sc; o[i][3] *= sc;
      s[i][0] = p0; s[i][1] = p1; s[i][2] = p2; s[i][3] = p3;
    }

#pragma unroll
    for (int jj = 0; jj < 4; jj++) {
      float4 pv = make_float4(s[0][jj], s[1][jj], s[2][jj], s[3][jj]);
      *(float4*)&Pt[tj * 4 + jj][ti * 4] = pv;
    }
    __syncthreads();

#pragma unroll 4
    for (int j = 0; j < 64; j++) {
      float pa[4], vb[4];
      *(float4*)pa = *(const float4*)&Pt[j][ti * 4];
      *(float4*)vb = *(const float4*)&Vs[j][tj * 4];
#pragma unroll
      for (int i = 0; i < 4; i++)
#pragma unroll
        for (int jc = 0; jc < 4; jc++)
          o[i][jc] = fmaf(pa[i], vb[jc], o[i][jc]);
    }
  }

#pragma unroll
  for (int i = 0; i < 4; i++) {
    float inv = 1.0f / l[i];
    ushort4 v;
    v.x = f2b(o[i][0] * inv); v.y = f2b(o[i][1] * inv);
    v.z = f2b(o[i][2] * inv); v.w = f2b(o[i][3] * inv);
    size_t row = (size_t)(b * S_ + q0 + ti * 4 + i);
    *(ushort4*)(concat + row * 1024 + h * 64 + tj * 4) = v;
  }
}

// ---------------------------------------------------------------------------
// y = LayerNorm(a + r); optionally also write bf16 copy yb
// ---------------------------------------------------------------------------
template <int WBF>
__global__ __launch_bounds__(256) void add_ln_k(const float* __restrict__ a,
                                                const float* __restrict__ r,
                                                float* __restrict__ y,
                                                ushort* __restrict__ yb) {
  const int row = blockIdx.x, t = threadIdx.x;
  const float4 av = ((const float4*)(a + (size_t)row * 1024))[t];
  const float4 rv = ((const float4*)(r + (size_t)row * 1024))[t];
  float v[4] = {av.x + rv.x, av.y + rv.y, av.z + rv.z, av.w + rv.w};
  float s = v[0] + v[1] + v[2] + v[3];
  float q = v[0] * v[0] + v[1] * v[1] + v[2] * v[2] + v[3] * v[3];
#pragma unroll
  for (int off = 1; off < 64; off <<= 1) {
    s += __shfl_xor(s, off);
    q += __shfl_xor(q, off);
  }
  __shared__ float ss[4], sq[4];
  int wave = t >> 6, lane = t & 63;
  if (lane == 0) { ss[wave] = s; sq[wave] = q; }
  __syncthreads();
  s = ss[0] + ss[1] + ss[2] + ss[3];
  q = sq[0] + sq[1] + sq[2] + sq[3];
  float mean = s * (1.f / 1024.f);
  float var = q * (1.f / 1024.f) - mean * mean;
  float inv = 1.0f / sqrtf(var + EPS_);
  float4 yo;
  yo.x = (v[0] - mean) * inv; yo.y = (v[1] - mean) * inv;
  yo.z = (v[2] - mean) * inv; yo.w = (v[3] - mean) * inv;
  ((float4*)(y + (size_t)row * 1024))[t] = yo;
  if (WBF) {
    ushort4 ob;
    ob.x = f2b(yo.x); ob.y = f2b(yo.y); ob.z = f2b(yo.z); ob.w = f2b(yo.w);
    ((ushort4*)(yb + (size_t)row * 1024))[t] = ob;
  }
}

// ---------------------------------------------------------------------------
extern "C" void kernel_launch(void* const* d_in, const int* in_sizes, int n_in,
                              void* d_out, int out_size, void* d_ws, size_t ws_size,
                              hipStream_t stream) {
  const float* x  = (const float*)d_in[0];
  const int* len  = (const int*)d_in[1];
  const float* Wq = (const float*)d_in[2];
  const float* Wk = (const float*)d_in[3];
  const float* Wv = (const float*)d_in[4];
  const float* Wo = (const float*)d_in[5];
  const float* W1 = (const float*)d_in[6];
  const float* b1 = (const float*)d_in[7];
  const float* W2 = (const float*)d_in[8];
  const float* b2 = (const float*)d_in[9];
  float* out = (float*)d_out;

  if (ws_size < (size_t)184 * 1024 * 1024) return;
  char* w = (char*)d_ws;
  ushort* xbf    = (ushort*)(w);                        // 16MB
  ushort* qkvw   = (ushort*)(w + ((size_t)16 << 20));   // 6MB
  ushort* wob    = (ushort*)(w + ((size_t)22 << 20));   // 2MB
  ushort* w1b    = (ushort*)(w + ((size_t)24 << 20));   // 8MB
  ushort* w2b    = (ushort*)(w + ((size_t)32 << 20));   // 8MB
  ushort* qkv    = (ushort*)(w + ((size_t)40 << 20));   // 48MB
  ushort* concat = (ushort*)(w + ((size_t)88 << 20));   // 16MB
  float*  attno  = (float*) (w + ((size_t)104 << 20));  // 32MB
  float*  x1     = (float*) (w + ((size_t)136 << 20));  // 32MB
  ushort* x1b    = (ushort*)(w + ((size_t)168 << 20));  // 16MB
  ushort* hidden = (ushort*)(w + ((size_t)40 << 20));   // 64MB (reuse qkv+concat)
  float*  ffn2o  = (float*) (w + ((size_t)104 << 20));  // 32MB (reuse attno)

  cast_bf16_k<<<8192, 256, 0, stream>>>(x, xbf, 2097152);
  pack_qkvT_k<<<12288, 256, 0, stream>>>(Wq, Wk, Wv, qkvw);
  cast_bf16_k<<<1024, 256, 0, stream>>>(Wo, wob, 262144);
  cast_bf16_k<<<4096, 256, 0, stream>>>(W1, w1b, 1048576);
  cast_bf16_k<<<4096, 256, 0, stream>>>(W2, w2b, 1048576);

  // QKV projection: [8192,1024] @ [3072,1024]^T -> bf16
  gemm_bf16<0, 0, 1><<<64 * 24, 256, 0, stream>>>(xbf, qkvw, nullptr, qkv,
                                                  8192, 3072, 1024);
  attention_k<<<2048, 256, 0, stream>>>(qkv, len, concat);
  // output projection -> fp32
  gemm_bf16<0, 0, 0><<<64 * 8, 256, 0, stream>>>(concat, wob, nullptr, attno,
                                                 8192, 1024, 1024);
  add_ln_k<1><<<8192, 256, 0, stream>>>(x, attno, x1, x1b);
  // FFN1 + bias + relu -> bf16
  gemm_bf16<1, 1, 1><<<64 * 32, 256, 0, stream>>>(x1b, w1b, b1, hidden,
                                                  8192, 4096, 1024);
  // FFN2 + bias -> fp32
  gemm_bf16<1, 0, 0><<<64 * 8, 256, 0, stream>>>(hidden, w2b, b2, ffn2o,
                                                 8192, 1024, 4096);
  add_ln_k<0><<<8192, 256, 0, stream>>>(x1, ffn2o, out, nullptr);
}

// Round 4
// 490.454 us; speedup vs baseline: 6.1136x; 1.6388x over previous
//
#include <hip/hip_runtime.h>
#include <hip/hip_bf16.h>
#include <math.h>

#define B_ 8
#define S_ 1024
#define D_ 1024
#define H_ 16
#define DH_ 64
#define FFN_ 4096
#define NEG_ (-1e9f)
#define EPS_ 1e-5f

typedef float f32x4 __attribute__((ext_vector_type(4)));
typedef short bf16x8 __attribute__((ext_vector_type(8)));

__device__ __forceinline__ ushort f2b(float f) {
  __hip_bfloat16 h = __float2bfloat16(f);  // RNE
  return *reinterpret_cast<ushort*>(&h);
}
__device__ __forceinline__ float b2f(ushort u) {
  return __uint_as_float((unsigned)u << 16);
}

__device__ __forceinline__ void gload16(const void* g, void* l) {
  auto* lp = (__attribute__((address_space(3))) unsigned*)(uintptr_t)(l);
  __builtin_amdgcn_global_load_lds(
      (const __attribute__((address_space(1))) unsigned*)g, lp, 16, 0, 0);
}

// XOR swizzle for [*][64]-ushort LDS tiles (128B row stride): spreads the
// 16-rows-same-column fragment read across 8 bank slots (G4 / T2).
__device__ __forceinline__ void* swz_ptr(void* base, int row, int col) {
  int byte = (row << 7) + (col << 1);
  byte ^= (row & 7) << 4;
  return (char*)base + byte;
}

// ---------------------------------------------------------------------------
// casts / packing
// ---------------------------------------------------------------------------
__global__ __launch_bounds__(256) void cast_bf16_k(const float* __restrict__ in,
                                                   ushort* __restrict__ out,
                                                   int n4) {
  int i = blockIdx.x * 256 + threadIdx.x;
  if (i >= n4) return;
  float4 v = ((const float4*)in)[i];
  ushort4 o;
  o.x = f2b(v.x); o.y = f2b(v.y); o.z = f2b(v.z); o.w = f2b(v.w);
  ((ushort4*)out)[i] = o;
}

// qkvT[(which*1024 + h*64 + e)][k] = W{q,k,v}[h][k][e]   (bf16 out)
__global__ __launch_bounds__(256) void pack_qkvT_k(
    const float* __restrict__ Wq, const float* __restrict__ Wk,
    const float* __restrict__ Wv, ushort* __restrict__ out) {
  int idx = blockIdx.x * 256 + threadIdx.x;  // 3*16*1024*64
  int e = idx & 63, k = (idx >> 6) & 1023;
  int h = (idx >> 16) & 15, which = idx >> 20;
  const float* W = (which == 0) ? Wq : (which == 1 ? Wk : Wv);
  float v = W[((size_t)h * D_ + k) * DH_ + e];
  out[((size_t)which * 1024 + h * 64 + e) * 1024 + k] = f2b(v);
}

// ---------------------------------------------------------------------------
// bf16 MFMA GEMM (m97 structure): C[M][N] = act(A[M][K] @ Bt[N][K]^T + bias)
// 128x128 tile, BK=64, 256 thr = 4 waves (2x2), 64x64 per wave, 16x16x32 MFMA
// ---------------------------------------------------------------------------
template <int BIAS, int RELU, int OUT_BF16>
__global__ __launch_bounds__(256) void gemm_bf16(
    const ushort* __restrict__ A, const ushort* __restrict__ Bt,
    const float* __restrict__ bias, void* __restrict__ C,
    int M, int N, int K) {
  __shared__ ushort Al[128 * 64];
  __shared__ ushort Bl[128 * 64];
  const int nb = N >> 7;
  const int bm = blockIdx.x / nb, bn = blockIdx.x % nb;
  const int t = threadIdx.x;
  const int lane = t & 63;
  const int wid = t >> 6, wr = wid >> 1, wc = wid & 1;
  const int row0 = bm << 7, col0 = bn << 7;
  const size_t Kb = (size_t)K * 2;  // row stride bytes

  const char* Abase = (const char*)A + (size_t)row0 * Kb;
  const char* Bbase = (const char*)Bt + (size_t)col0 * Kb;

  f32x4 acc[4][4] = {};

  const int o0 = t * 16;  // linear byte offset this thread stages
  for (int k0 = 0; k0 < K; k0 += 64) {
#pragma unroll
    for (int i = 0; i < 4; i++) {
      int ob = o0 + i * 4096;
      int row = ob >> 7, inrow = ob & 127;
      const char* ga = Abase + (size_t)row * Kb + k0 * 2 + inrow;
      const char* gb = Bbase + (size_t)row * Kb + k0 * 2 + inrow;
      gload16(ga, (char*)Al + ob);
      gload16(gb, (char*)Bl + ob);
    }
    __syncthreads();
#pragma unroll
    for (int kk = 0; kk < 64; kk += 32) {
      bf16x8 af[4], bfr[4];
      const int lrow = lane & 15, lk = (lane >> 4) * 8 + kk;
#pragma unroll
      for (int m = 0; m < 4; m++)
        af[m] = *(const bf16x8*)&Al[(wr * 64 + m * 16 + lrow) * 64 + lk];
#pragma unroll
      for (int n = 0; n < 4; n++)
        bfr[n] = *(const bf16x8*)&Bl[(wc * 64 + n * 16 + lrow) * 64 + lk];
#pragma unroll
      for (int m = 0; m < 4; m++)
#pragma unroll
        for (int n = 0; n < 4; n++)
          acc[m][n] = __builtin_amdgcn_mfma_f32_16x16x32_bf16(
              af[m], bfr[n], acc[m][n], 0, 0, 0);
    }
    __syncthreads();
  }

  // epilogue: C/D layout col=lane&15, row=(lane>>4)*4+q
  const int rbase = row0 + wr * 64 + (lane >> 4) * 4;
  const int cbase = col0 + wc * 64 + (lane & 15);
#pragma unroll
  for (int m = 0; m < 4; m++) {
#pragma unroll
    for (int n = 0; n < 4; n++) {
      int col = cbase + n * 16;
      float bv = BIAS ? bias[col] : 0.0f;
#pragma unroll
      for (int q = 0; q < 4; q++) {
        int row = rbase + m * 16 + q;
        float v = acc[m][n][q] + bv;
        if (RELU) v = fmaxf(v, 0.0f);
        if (OUT_BF16)
          ((ushort*)C)[(size_t)row * N + col] = f2b(v);
        else
          ((float*)C)[(size_t)row * N + col] = v;
      }
    }
  }
}

// ---------------------------------------------------------------------------
// MFMA flash attention over bf16 qkv [B*S][3072] (q|k|v, each h*64+e).
// One block per (b, h, 64-row q-tile); 4 waves, each owning 16 q-rows.
// QK^T and PV via mfma_f32_16x16x32_bf16; online softmax in-register;
// P -> bf16 via per-wave LDS round trip. All LDS tiles XOR-swizzled.
// ---------------------------------------------------------------------------
__global__ __launch_bounds__(256) void attention_mfma_k(
    const ushort* __restrict__ qkv, const int* __restrict__ lens,
    ushort* __restrict__ concat) {
  __shared__ ushort Qs[64 * 64];
  __shared__ ushort Ks[64 * 64];
  __shared__ ushort Vt[64 * 64];      // V transposed: [d][key]
  __shared__ ushort Pl[4][16 * 64];   // per-wave P tile [qrow][key]
  const int blk = blockIdx.x;
  const int b = blk >> 8, rem = blk & 255;
  const int h = rem >> 4, q0 = (rem & 15) << 6;
  const int t = threadIdx.x;
  const int lane = t & 63, w = t >> 6;
  const int lr = lane & 15, lg = lane >> 4;
  const int len_b = lens[b];
  ushort* Plw = &Pl[w][0];

  // load Q tile (row-major, swizzled)
#pragma unroll
  for (int i = 0; i < 4; i++) {
    int idx = t + i * 256;
    int r = idx >> 4, eq = idx & 15;
    const ushort* src =
        qkv + ((size_t)(b * S_ + q0 + r)) * 3072 + h * 64 + eq * 4;
    *(ushort4*)swz_ptr(Qs, r, eq * 4) = *(const ushort4*)src;
  }
  __syncthreads();
  bf16x8 qf[2];
#pragma unroll
  for (int ds = 0; ds < 2; ds++)
    qf[ds] = *(const bf16x8*)swz_ptr(Qs, w * 16 + lr, lg * 8 + ds * 32);

  float m[4], l[4];
  f32x4 o[4] = {};  // o[dt][q] : col = dt*16+lr, row = lg*4+q
#pragma unroll
  for (int q = 0; q < 4; q++) { m[q] = -INFINITY; l[q] = 0.f; }

  for (int j0 = 0; j0 < len_b; j0 += 64) {
    __syncthreads();  // previous iter's Ks/Vt reads done
#pragma unroll
    for (int i = 0; i < 4; i++) {
      int idx = t + i * 256;
      int r = idx >> 4, eq = idx & 15;
      const ushort* base =
          qkv + ((size_t)(b * S_ + j0 + r)) * 3072 + h * 64 + eq * 4;
      *(ushort4*)swz_ptr(Ks, r, eq * 4) = *(const ushort4*)(base + 1024);
      ushort4 vv = *(const ushort4*)(base + 2048);
      *(ushort*)swz_ptr(Vt, eq * 4 + 0, r) = vv.x;
      *(ushort*)swz_ptr(Vt, eq * 4 + 1, r) = vv.y;
      *(ushort*)swz_ptr(Vt, eq * 4 + 2, r) = vv.z;
      *(ushort*)swz_ptr(Vt, eq * 4 + 3, r) = vv.w;
    }
    __syncthreads();

    // QK^T: S[16q x 64k] per wave
    f32x4 sacc[4];
#pragma unroll
    for (int n = 0; n < 4; n++) {
      sacc[n] = (f32x4){0.f, 0.f, 0.f, 0.f};
#pragma unroll
      for (int ds = 0; ds < 2; ds++) {
        bf16x8 kf = *(const bf16x8*)swz_ptr(Ks, n * 16 + lr, lg * 8 + ds * 32);
        sacc[n] = __builtin_amdgcn_mfma_f32_16x16x32_bf16(qf[ds], kf, sacc[n],
                                                          0, 0, 0);
      }
    }

    // scale + mask + online softmax (rows = lg*4+q, cols = n*16+lr)
    float p[4][4];  // p[n][q]
#pragma unroll
    for (int q = 0; q < 4; q++) {
      float s[4];
#pragma unroll
      for (int n = 0; n < 4; n++) {
        s[n] = sacc[n][q] * 0.125f;
        if (j0 + n * 16 + lr >= len_b) s[n] = NEG_;
      }
      float a = fmaxf(fmaxf(s[0], s[1]), fmaxf(s[2], s[3]));
#pragma unroll
      for (int off = 1; off < 16; off <<= 1) a = fmaxf(a, __shfl_xor(a, off));
      float mn = fmaxf(m[q], a);
      float sc = __expf(m[q] - mn);
      float rs = 0.f;
#pragma unroll
      for (int n = 0; n < 4; n++) {
        p[n][q] = __expf(s[n] - mn);
        rs += p[n][q];
      }
#pragma unroll
      for (int off = 1; off < 16; off <<= 1) rs += __shfl_xor(rs, off);
      l[q] = l[q] * sc + rs;
      m[q] = mn;
#pragma unroll
      for (int dt = 0; dt < 4; dt++) o[dt][q] *= sc;
    }

    // P -> bf16 -> per-wave LDS (no cross-wave barrier needed)
#pragma unroll
    for (int n = 0; n < 4; n++)
#pragma unroll
      for (int q = 0; q < 4; q++)
        *(ushort*)swz_ptr(Plw, lg * 4 + q, n * 16 + lr) = f2b(p[n][q]);

    // PV: O[16q x 64d] += P[16q x 64k] @ V[64k x 64d]
    bf16x8 pf[2];
#pragma unroll
    for (int ks = 0; ks < 2; ks++)
      pf[ks] = *(const bf16x8*)swz_ptr(Plw, lr, lg * 8 + ks * 32);
#pragma unroll
    for (int dt = 0; dt < 4; dt++) {
#pragma unroll
      for (int ks = 0; ks < 2; ks++) {
        bf16x8 vf = *(const bf16x8*)swz_ptr(Vt, dt * 16 + lr, lg * 8 + ks * 32);
        o[dt] = __builtin_amdgcn_mfma_f32_16x16x32_bf16(pf[ks], vf, o[dt],
                                                        0, 0, 0);
      }
    }
  }

  // epilogue
#pragma unroll
  for (int q = 0; q < 4; q++) {
    float inv = 1.0f / l[q];
    size_t row = (size_t)(b * S_ + q0 + w * 16 + lg * 4 + q);
#pragma unroll
    for (int dt = 0; dt < 4; dt++)
      concat[row * 1024 + h * 64 + dt * 16 + lr] = f2b(o[dt][q] * inv);
  }
}

// ---------------------------------------------------------------------------
// y = LayerNorm(a + r); optionally also write bf16 copy yb
// ---------------------------------------------------------------------------
template <int WBF>
__global__ __launch_bounds__(256) void add_ln_k(const float* __restrict__ a,
                                                const float* __restrict__ r,
                                                float* __restrict__ y,
                                                ushort* __restrict__ yb) {
  const int row = blockIdx.x, t = threadIdx.x;
  const float4 av = ((const float4*)(a + (size_t)row * 1024))[t];
  const float4 rv = ((const float4*)(r + (size_t)row * 1024))[t];
  float v[4] = {av.x + rv.x, av.y + rv.y, av.z + rv.z, av.w + rv.w};
  float s = v[0] + v[1] + v[2] + v[3];
  float q = v[0] * v[0] + v[1] * v[1] + v[2] * v[2] + v[3] * v[3];
#pragma unroll
  for (int off = 1; off < 64; off <<= 1) {
    s += __shfl_xor(s, off);
    q += __shfl_xor(q, off);
  }
  __shared__ float ss[4], sq[4];
  int wave = t >> 6, lane = t & 63;
  if (lane == 0) { ss[wave] = s; sq[wave] = q; }
  __syncthreads();
  s = ss[0] + ss[1] + ss[2] + ss[3];
  q = sq[0] + sq[1] + sq[2] + sq[3];
  float mean = s * (1.f / 1024.f);
  float var = q * (1.f / 1024.f) - mean * mean;
  float inv = 1.0f / sqrtf(var + EPS_);
  float4 yo;
  yo.x = (v[0] - mean) * inv; yo.y = (v[1] - mean) * inv;
  yo.z = (v[2] - mean) * inv; yo.w = (v[3] - mean) * inv;
  ((float4*)(y + (size_t)row * 1024))[t] = yo;
  if (WBF) {
    ushort4 ob;
    ob.x = f2b(yo.x); ob.y = f2b(yo.y); ob.z = f2b(yo.z); ob.w = f2b(yo.w);
    ((ushort4*)(yb + (size_t)row * 1024))[t] = ob;
  }
}

// ---------------------------------------------------------------------------
extern "C" void kernel_launch(void* const* d_in, const int* in_sizes, int n_in,
                              void* d_out, int out_size, void* d_ws, size_t ws_size,
                              hipStream_t stream) {
  const float* x  = (const float*)d_in[0];
  const int* len  = (const int*)d_in[1];
  const float* Wq = (const float*)d_in[2];
  const float* Wk = (const float*)d_in[3];
  const float* Wv = (const float*)d_in[4];
  const float* Wo = (const float*)d_in[5];
  const float* W1 = (const float*)d_in[6];
  const float* b1 = (const float*)d_in[7];
  const float* W2 = (const float*)d_in[8];
  const float* b2 = (const float*)d_in[9];
  float* out = (float*)d_out;

  if (ws_size < (size_t)184 * 1024 * 1024) return;
  char* w = (char*)d_ws;
  ushort* xbf    = (ushort*)(w);                        // 16MB
  ushort* qkvw   = (ushort*)(w + ((size_t)16 << 20));   // 6MB
  ushort* wob    = (ushort*)(w + ((size_t)22 << 20));   // 2MB
  ushort* w1b    = (ushort*)(w + ((size_t)24 << 20));   // 8MB
  ushort* w2b    = (ushort*)(w + ((size_t)32 << 20));   // 8MB
  ushort* qkv    = (ushort*)(w + ((size_t)40 << 20));   // 48MB
  ushort* concat = (ushort*)(w + ((size_t)88 << 20));   // 16MB
  float*  attno  = (float*) (w + ((size_t)104 << 20));  // 32MB
  float*  x1     = (float*) (w + ((size_t)136 << 20));  // 32MB
  ushort* x1b    = (ushort*)(w + ((size_t)168 << 20));  // 16MB
  ushort* hidden = (ushort*)(w + ((size_t)40 << 20));   // 64MB (reuse qkv+concat)
  float*  ffn2o  = (float*) (w + ((size_t)104 << 20));  // 32MB (reuse attno)

  cast_bf16_k<<<8192, 256, 0, stream>>>(x, xbf, 2097152);
  pack_qkvT_k<<<12288, 256, 0, stream>>>(Wq, Wk, Wv, qkvw);
  cast_bf16_k<<<1024, 256, 0, stream>>>(Wo, wob, 262144);
  cast_bf16_k<<<4096, 256, 0, stream>>>(W1, w1b, 1048576);
  cast_bf16_k<<<4096, 256, 0, stream>>>(W2, w2b, 1048576);

  // QKV projection: [8192,1024] @ [3072,1024]^T -> bf16
  gemm_bf16<0, 0, 1><<<64 * 24, 256, 0, stream>>>(xbf, qkvw, nullptr, qkv,
                                                  8192, 3072, 1024);
  attention_mfma_k<<<2048, 256, 0, stream>>>(qkv, len, concat);
  // output projection -> fp32
  gemm_bf16<0, 0, 0><<<64 * 8, 256, 0, stream>>>(concat, wob, nullptr, attno,
                                                 8192, 1024, 1024);
  add_ln_k<1><<<8192, 256, 0, stream>>>(x, attno, x1, x1b);
  // FFN1 + bias + relu -> bf16
  gemm_bf16<1, 1, 1><<<64 * 32, 256, 0, stream>>>(x1b, w1b, b1, hidden,
                                                  8192, 4096, 1024);
  // FFN2 + bias -> fp32
  gemm_bf16<1, 0, 0><<<64 * 8, 256, 0, stream>>>(hidden, w2b, b2, ffn2o,
                                                 8192, 1024, 4096);
  add_ln_k<0><<<8192, 256, 0, stream>>>(x1, ffn2o, out, nullptr);
}